// Round 11
// baseline (40.938 us; speedup 1.0000x reference)
//
#include <hip/hip_runtime.h>

// Problem constants
#define BB 8
#define SS 2048
#define FF 256
#define HH 8
#define DD 64
#define PROJ 512
#define NCHUNK 32
#define CHUNK (SS / NCHUNK) // 64

// ---------------------------------------------------------------------------
// N1: k_qr, grid = B*H = 64, block = 256.
//  q_h = x[b,S-1,:] @ Wq_h ; r[b,h,f] = (1/8) * Wk_h q_h
// ---------------------------------------------------------------------------
__global__ void __launch_bounds__(256) k_qr(
    const float* __restrict__ x, const float* __restrict__ Wq,
    const float* __restrict__ Wk, float* __restrict__ r) {
    const int b = blockIdx.x / HH;
    const int h = blockIdx.x % HH;
    const int t = threadIdx.x;
    __shared__ float xrow[FF];
    __shared__ float qp[4][DD];
    __shared__ float qh[DD];

    xrow[t] = x[((size_t)b * SS + (SS - 1)) * FF + t];
    __syncthreads();

    // q partials: t = g*64 + d ; group g covers f in [g*64, g*64+64)
    {
        const int g = t >> 6, d = t & 63;
        float acc = 0.f;
        const float* wqp = Wq + (size_t)(g * 64) * PROJ + h * DD + d;
#pragma unroll 8
        for (int j = 0; j < 64; ++j)
            acc += xrow[g * 64 + j] * wqp[(size_t)j * PROJ];
        qp[g][d] = acc;
    }
    __syncthreads();
    if (t < DD) qh[t] = qp[0][t] + qp[1][t] + qp[2][t] + qp[3][t];
    __syncthreads();

    const float4* wk4 = reinterpret_cast<const float4*>(Wk + (size_t)t * PROJ + h * DD);
    float acc = 0.f;
#pragma unroll
    for (int d4 = 0; d4 < DD / 4; ++d4) {
        float4 w = wk4[d4];
        acc += w.x * qh[d4 * 4 + 0] + w.y * qh[d4 * 4 + 1] +
               w.z * qh[d4 * 4 + 2] + w.w * qh[d4 * 4 + 3];
    }
    r[(size_t)blockIdx.x * FF + t] = acc * 0.125f; // fold 1/sqrt(64)
}

// ---------------------------------------------------------------------------
// N2: k_chunks, grid = B*NCHUNK = 256, block = 512.
//  e[h][sl] = exp(x_row . r_h)  (no max subtraction: scores ~ N(0,1) by
//  construction, |score| << 88 fp32-exp limit; softmax is shift-invariant)
//  lpart[b,c,h] = sum_sl e ; ycp[b,c,h,f] = sum_sl e * x[row, f]
// ---------------------------------------------------------------------------
__global__ void __launch_bounds__(512) k_chunks(
    const float* __restrict__ x, const float* __restrict__ r,
    float* __restrict__ ycp, float* __restrict__ lpart) {
    const int b = blockIdx.x / NCHUNK;
    const int c = blockIdx.x % NCHUNK;
    const int t = threadIdx.x;
    __shared__ float rl[HH][FF + 4];    // 8.3 KB
    __shared__ float es[HH][CHUNK + 4]; // 2.2 KB exp weights
    __shared__ float yp[2][HH][FF];     // 16 KB

    for (int i = t; i < HH * FF; i += 512)
        rl[i >> 8][i & 255] = r[(size_t)b * HH * FF + i];
    __syncthreads();

    // scores -> exp: t = sl*8 + h
    {
        const int sl = t >> 3, h = t & 7;
        const float4* xp = reinterpret_cast<const float4*>(
            x + ((size_t)b * SS + c * CHUNK + sl) * FF);
        const float* rp = rl[h];
        float acc = 0.f;
#pragma unroll 8
        for (int f4 = 0; f4 < FF / 4; ++f4) {
            float4 xv = xp[f4];
            acc += xv.x * rp[f4 * 4 + 0] + xv.y * rp[f4 * 4 + 1] +
                   xv.z * rp[f4 * 4 + 2] + xv.w * rp[f4 * 4 + 3];
        }
        es[h][sl] = __expf(acc);
    }
    __syncthreads();

    // denominator partial: wave wv owns head wv
    {
        const int h = t >> 6, ln = t & 63;
        float l = es[h][ln];
#pragma unroll
        for (int off = 32; off; off >>= 1) l += __shfl_xor(l, off);
        if (ln == 0) lpart[((size_t)(b * NCHUNK + c)) * HH + h] = l;
    }
    // no barrier needed: es is read-only from here on

    // weighted x-sum: t = half*256 + f ; halves cover 32 s each
    {
        const int f = t & 255, half = t >> 8;
        float acc[HH] = {0, 0, 0, 0, 0, 0, 0, 0};
        const float* xp = x + ((size_t)b * SS + c * CHUNK + half * 32) * FF + f;
        for (int s = 0; s < 32; ++s) {
            const float xv = xp[(size_t)s * FF];
            const int sl = half * 32 + s;
#pragma unroll
            for (int h = 0; h < HH; ++h) acc[h] += es[h][sl] * xv;
        }
#pragma unroll
        for (int h = 0; h < HH; ++h) yp[half][h][f] = acc[h];
    }
    __syncthreads();

    for (int i = t; i < HH * FF; i += 512) {
        const int h = i >> 8, f = i & 255;
        ycp[((size_t)(b * NCHUNK + c) * HH + h) * FF + f] =
            yp[0][h][f] + yp[1][h][f];
    }
}

// ---------------------------------------------------------------------------
// N3: k_tail, grid = B*8 = 64 (fs = 32-col out slice), block = 512.
//  Each block redundantly: Linv[8] from lpart; ys[2048] = (sum_c ycp)*Linv;
//  at[512] = per-head ys_h . Wv_h ; out slice = bo + at . Wo[:, fs*32+32]
// ---------------------------------------------------------------------------
__global__ void __launch_bounds__(512) k_tail(
    const float* __restrict__ ycp, const float* __restrict__ lpart,
    const float* __restrict__ Wv, const float* __restrict__ Wo,
    const float* __restrict__ bo, float* __restrict__ out) {
    const int b  = blockIdx.x >> 3;
    const int fs = blockIdx.x & 7;
    const int t  = threadIdx.x;
    __shared__ float Linv[HH];
    __shared__ float ys[HH * FF];  // 8 KB
    __shared__ float at[PROJ];     // 2 KB
    __shared__ float po[16][32];   // 2 KB

    // Linv: t<256 -> (h = t>>5, c = t&31); 32-lane half-wave reduce
    if (t < 256) {
        const int h = t >> 5, c = t & 31;
        float l = lpart[((size_t)(b * NCHUNK + c)) * HH + h];
#pragma unroll
        for (int off = 16; off; off >>= 1) l += __shfl_xor(l, off);
        if (c == 0) Linv[h] = 1.f / l;
    }
    __syncthreads();

    // combine chunks -> normalized y in LDS (4 iters of 512 threads)
    for (int i = t; i < HH * FF; i += 512) {
        const int h = i >> 8, f = i & 255;
        const float* yb = ycp + ((size_t)(b * NCHUNK) * HH + h) * FF + f;
        float acc = 0.f;
#pragma unroll 8
        for (int c = 0; c < NCHUNK; ++c)
            acc += yb[(size_t)c * HH * FF];
        ys[i] = acc * Linv[h];
    }
    __syncthreads();

    // attn projection: t -> (h = t>>6, d = t&63), coalesced Wv rows
    {
        const int h = t >> 6, d = t & 63;
        float acc = 0.f;
        const float* wvp = Wv + h * DD + d;
        const float* yh = ys + h * FF;
#pragma unroll 8
        for (int f = 0; f < FF; ++f)
            acc += yh[f] * wvp[(size_t)f * PROJ];
        at[t] = acc;
    }
    __syncthreads();

    // out slice GEMV: t = pg*32 + j ; p-group pg covers p in [pg*32, pg*32+32)
    {
        const int j = t & 31, pg = t >> 5;
        float acc = 0.f;
        const float* wop = Wo + (size_t)(pg * 32) * FF + fs * 32 + j;
        const float* ap = at + pg * 32;
#pragma unroll 8
        for (int p = 0; p < 32; ++p)
            acc += ap[p] * wop[(size_t)p * FF];
        po[pg][j] = acc;
    }
    __syncthreads();

    if (t < 32) {
        float o = bo[fs * 32 + t];
#pragma unroll
        for (int pg = 0; pg < 16; ++pg) o += po[pg][t];
        out[(size_t)b * FF + fs * 32 + t] = o;
    }
}

// ---------------------------------------------------------------------------
extern "C" void kernel_launch(void* const* d_in, const int* in_sizes, int n_in,
                              void* d_out, int out_size, void* d_ws, size_t ws_size,
                              hipStream_t stream) {
    const float* x  = (const float*)d_in[0];
    const float* Wq = (const float*)d_in[1];
    const float* Wk = (const float*)d_in[2];
    const float* Wv = (const float*)d_in[3];
    const float* Wo = (const float*)d_in[4];
    const float* bo = (const float*)d_in[5];
    float* out = (float*)d_out;

    float* ws    = (float*)d_ws;
    float* r     = ws;                                  // B*H*F    = 16384
    float* ycp   = r + BB * HH * FF;                    // B*NC*H*F = 524288
    float* lpart = ycp + (size_t)BB * NCHUNK * HH * FF; // B*NC*H   = 2048

    k_qr<<<BB * HH, 256, 0, stream>>>(x, Wq, Wk, r);
    k_chunks<<<BB * NCHUNK, 512, 0, stream>>>(x, r, ycp, lpart);
    k_tail<<<BB * 8, 512, 0, stream>>>(ycp, lpart, Wv, Wo, bo, out);
}

// Round 12
// 36.126 us; speedup vs baseline: 1.1332x; 1.1332x over previous
//
#include <hip/hip_runtime.h>

// Problem constants
#define BB 8
#define SS 2048
#define FF 256
#define HH 8
#define DD 64
#define PROJ 512
#define NCHUNK 64
#define CHUNK (SS / NCHUNK) // 32

// ---------------------------------------------------------------------------
// N1: k_qr, grid = B*H = 64, block = 512 (8 waves for latency hiding).
//  q_h = x[b,S-1,:] @ Wq_h ; r[b,h,f] = (1/8) * Wk_h q_h
// ---------------------------------------------------------------------------
__global__ void __launch_bounds__(512) k_qr(
    const float* __restrict__ x, const float* __restrict__ Wq,
    const float* __restrict__ Wk, float* __restrict__ r) {
    const int b = blockIdx.x / HH;
    const int h = blockIdx.x % HH;
    const int t = threadIdx.x;
    __shared__ float xrow[FF];
    __shared__ float qp[8][DD];
    __shared__ float qh[DD];

    if (t < FF) xrow[t] = x[((size_t)b * SS + (SS - 1)) * FF + t];
    __syncthreads();

    // q partials: t = g*64 + d ; group g covers f in [g*32, g*32+32)
    {
        const int g = t >> 6, d = t & 63;
        float acc = 0.f;
        const float* wqp = Wq + (size_t)(g * 32) * PROJ + h * DD + d;
#pragma unroll 8
        for (int j = 0; j < 32; ++j)
            acc += xrow[g * 32 + j] * wqp[(size_t)j * PROJ];
        qp[g][d] = acc;
    }
    __syncthreads();
    if (t < DD) {
        float q = 0.f;
#pragma unroll
        for (int g = 0; g < 8; ++g) q += qp[g][t];
        qh[t] = q;
    }
    __syncthreads();

    if (t < FF) {
        const float4* wk4 =
            reinterpret_cast<const float4*>(Wk + (size_t)t * PROJ + h * DD);
        float acc = 0.f;
#pragma unroll
        for (int d4 = 0; d4 < DD / 4; ++d4) {
            float4 w = wk4[d4];
            acc += w.x * qh[d4 * 4 + 0] + w.y * qh[d4 * 4 + 1] +
                   w.z * qh[d4 * 4 + 2] + w.w * qh[d4 * 4 + 3];
        }
        r[(size_t)blockIdx.x * FF + t] = acc * 0.125f; // fold 1/sqrt(64)
    }
}

// ---------------------------------------------------------------------------
// N2: k_chunks, grid = B*NCHUNK = 512 (2 blocks/CU), block = 512.
//  32-row chunks. e[h][sl] = exp(x_row . r_h) (no max: scores ~ N(0,1)).
//  lpart[b,c,h] = sum_sl e ; ycp[b,c,h,f] = sum_sl e * x[row, f]
// ---------------------------------------------------------------------------
__global__ void __launch_bounds__(512) k_chunks(
    const float* __restrict__ x, const float* __restrict__ r,
    float* __restrict__ ycp, float* __restrict__ lpart) {
    const int b = blockIdx.x / NCHUNK;
    const int c = blockIdx.x % NCHUNK;
    const int t = threadIdx.x;
    __shared__ float rl[HH][FF + 4];   // 8.3 KB
    __shared__ float esp[512];         // 2 KB score half-partials
    __shared__ float es[HH][CHUNK + 4];// 1.2 KB exp weights
    __shared__ float yp[2][HH][FF];    // 16 KB

    for (int i = t; i < HH * FF; i += 512)
        rl[i >> 8][i & 255] = r[(size_t)b * HH * FF + i];
    __syncthreads();

    // phase 1: score half-partials. t -> sl = t>>4 (32 rows), h = (t>>1)&7,
    // fh = t&1 (two 128-float halves). esp[t] = partial dot.
    {
        const int fh = t & 1, h = (t >> 1) & 7, sl = t >> 4;
        const float4* xp = reinterpret_cast<const float4*>(
            x + ((size_t)b * SS + c * CHUNK + sl) * FF + fh * 128);
        const float* rp = rl[h] + fh * 128;
        float acc = 0.f;
#pragma unroll 8
        for (int f4 = 0; f4 < 32; ++f4) {
            float4 xv = xp[f4];
            acc += xv.x * rp[f4 * 4 + 0] + xv.y * rp[f4 * 4 + 1] +
                   xv.z * rp[f4 * 4 + 2] + xv.w * rp[f4 * 4 + 3];
        }
        esp[t] = acc; // t == sl*16 + h*2 + fh
    }
    __syncthreads();

    // phase 2: exp + denominator. wave w = head w; lanes 0..31 own rows.
    {
        const int h = t >> 6, ln = t & 63;
        float l = 0.f;
        if (ln < CHUNK) {
            const float v = esp[ln * 16 + h * 2 + 0] + esp[ln * 16 + h * 2 + 1];
            const float e = __expf(v);
            es[h][ln] = e;
            l = e;
        }
#pragma unroll
        for (int off = 32; off; off >>= 1) l += __shfl_xor(l, off);
        if (ln == 0) lpart[((size_t)(b * NCHUNK + c)) * HH + h] = l;
    }
    __syncthreads();

    // phase 3: weighted x-sum. t = half*256 + f ; halves cover 16 s each.
    {
        const int f = t & 255, half = t >> 8;
        float acc[HH] = {0, 0, 0, 0, 0, 0, 0, 0};
        const float* xp = x + ((size_t)b * SS + c * CHUNK + half * 16) * FF + f;
        for (int s = 0; s < 16; ++s) {
            const float xv = xp[(size_t)s * FF];
            const int sl = half * 16 + s;
#pragma unroll
            for (int h = 0; h < HH; ++h) acc[h] += es[h][sl] * xv;
        }
#pragma unroll
        for (int h = 0; h < HH; ++h) yp[half][h][f] = acc[h];
    }
    __syncthreads();

    for (int i = t; i < HH * FF; i += 512) {
        const int h = i >> 8, f = i & 255;
        ycp[((size_t)(b * NCHUNK + c) * HH + h) * FF + f] =
            yp[0][h][f] + yp[1][h][f];
    }
}

// ---------------------------------------------------------------------------
// N3: k_comb2, grid = B*H = 64, block = 512 (8 waves).
//  L = sum_c lpart ; y[f] = sum_c ycp ; attn_g[b,h*64+d] = (y . Wv_h[:,d]) / L
// ---------------------------------------------------------------------------
__global__ void __launch_bounds__(512) k_comb2(
    const float* __restrict__ ycp, const float* __restrict__ lpart,
    const float* __restrict__ Wv, float* __restrict__ attn_g) {
    const int b = blockIdx.x / HH;
    const int h = blockIdx.x % HH;
    const int t = threadIdx.x;
    __shared__ float yt[FF];
    __shared__ float atl[8][DD];
    __shared__ float Linv;

    // L: first wave reduces 64 chunk partials
    if (t < 64) {
        float l = lpart[((size_t)(b * NCHUNK + t)) * HH + h];
#pragma unroll
        for (int off = 32; off; off >>= 1) l += __shfl_xor(l, off);
        if (t == 0) Linv = 1.f / l;
    }

    // y combine: t<256 = f; 64 chunks, stride HH*FF
    if (t < FF) {
        float a0 = 0.f, a1 = 0.f;
        const float* yb = ycp + ((size_t)(b * NCHUNK) * HH + h) * FF + t;
#pragma unroll 8
        for (int c = 0; c < NCHUNK; c += 2) {
            a0 += yb[(size_t)c * HH * FF];
            a1 += yb[(size_t)(c + 1) * HH * FF];
        }
        yt[t] = a0 + a1;
    }
    __syncthreads();

    // Wv projection: t = q8*64 + d ; group q8 covers f in [q8*32, q8*32+32)
    {
        const int q8 = t >> 6, d = t & 63;
        float acc = 0.f;
        const float* wvp = Wv + (size_t)(q8 * 32) * PROJ + h * DD + d;
#pragma unroll 8
        for (int j = 0; j < 32; ++j)
            acc += yt[q8 * 32 + j] * wvp[(size_t)j * PROJ];
        atl[q8][d] = acc;
    }
    __syncthreads();

    if (t < DD) {
        float acc = 0.f;
#pragma unroll
        for (int q8 = 0; q8 < 8; ++q8) acc += atl[q8][t];
        attn_g[(size_t)b * PROJ + h * DD + t] = acc * Linv;
    }
}

// ---------------------------------------------------------------------------
// N4: k_out, grid = B*16 = 128 (fs = 16-col f-slice), block = 256.
//  out[b, fs*16+j] = bo + sum_p attn_g[b,p] * Wo[p, fs*16+j]
//  Per block: 32 KB Wo slice. t = pg*16 + j ; p-group pg covers 32 p.
// ---------------------------------------------------------------------------
__global__ void __launch_bounds__(256) k_out(
    const float* __restrict__ attn_g, const float* __restrict__ Wo,
    const float* __restrict__ bo, float* __restrict__ out) {
    const int b  = blockIdx.x >> 4;
    const int fs = blockIdx.x & 15;
    const int t  = threadIdx.x;
    __shared__ float al[PROJ];   // 2 KB
    __shared__ float po[16][16]; // 1 KB

    for (int i = t; i < PROJ; i += 256) al[i] = attn_g[(size_t)b * PROJ + i];
    __syncthreads();

    {
        const int j = t & 15, pg = t >> 4;
        float acc = 0.f;
        const float* wop = Wo + (size_t)(pg * 32) * FF + fs * 16 + j;
        const float* ap = al + pg * 32;
#pragma unroll 8
        for (int p = 0; p < 32; ++p)
            acc += ap[p] * wop[(size_t)p * FF];
        po[pg][j] = acc;
    }
    __syncthreads();

    if (t < 16) {
        float o = bo[fs * 16 + t];
#pragma unroll
        for (int pg = 0; pg < 16; ++pg) o += po[pg][t];
        out[(size_t)b * FF + fs * 16 + t] = o;
    }
}

// ---------------------------------------------------------------------------
extern "C" void kernel_launch(void* const* d_in, const int* in_sizes, int n_in,
                              void* d_out, int out_size, void* d_ws, size_t ws_size,
                              hipStream_t stream) {
    const float* x  = (const float*)d_in[0];
    const float* Wq = (const float*)d_in[1];
    const float* Wk = (const float*)d_in[2];
    const float* Wv = (const float*)d_in[3];
    const float* Wo = (const float*)d_in[4];
    const float* bo = (const float*)d_in[5];
    float* out = (float*)d_out;

    float* ws     = (float*)d_ws;
    float* r      = ws;                                  // B*H*F    = 16384
    float* ycp    = r + BB * HH * FF;                    // B*NC*H*F = 1048576
    float* lpart  = ycp + (size_t)BB * NCHUNK * HH * FF; // B*NC*H   = 4096
    float* attn_g = lpart + BB * NCHUNK * HH;            // B*PROJ   = 4096

    k_qr<<<BB * HH, 512, 0, stream>>>(x, Wq, Wk, r);
    k_chunks<<<BB * NCHUNK, 512, 0, stream>>>(x, r, ycp, lpart);
    k_comb2<<<BB * HH, 512, 0, stream>>>(ycp, lpart, Wv, attn_g);
    k_out<<<BB * 16, 256, 0, stream>>>(attn_g, Wo, bo, out);
}